// Round 11
// baseline (519.452 us; speedup 1.0000x reference)
//
#include <hip/hip_runtime.h>
#include <math.h>

#define D_MODEL 1024
#define D_INNER 2048
#define D_STATE 16
#define DT_RANK 64
#define BSZ 2
#define SEQ 2048
#define NTOK (BSZ*SEQ)     // 4096
#define NCH  (BSZ*D_INNER) // 4096 channels
#define NCHUNK 64
#define CLEN 32            // SEQ / NCHUNK
#define EPS 1e-5f

typedef __attribute__((ext_vector_type(8))) short short8v;
typedef __attribute__((ext_vector_type(4))) float f32x4;

__device__ __forceinline__ float sgnf(float w) {
    return (w > 0.f) ? 1.f : ((w < 0.f) ? -1.f : 0.f);
}
__device__ __forceinline__ unsigned short f2bf(float f) {   // RNE fp32->bf16
    unsigned int x = __float_as_uint(f);
    x += 0x7fffu + ((x >> 16) & 1u);
    return (unsigned short)(x >> 16);
}
__device__ __forceinline__ float bf2f(unsigned short u) {
    return __uint_as_float(((unsigned int)u) << 16);
}
__device__ __forceinline__ void stage16(const unsigned short* g, unsigned short* l) {
    __builtin_amdgcn_global_load_lds(
        (const __attribute__((address_space(1))) unsigned int*)g,
        (__attribute__((address_space(3))) unsigned int*)l, 16, 0, 0);
}
#define LDv(p) (*reinterpret_cast<const short8v*>(p))

// ------------------- merged weight conversion (6 tensors, 1 launch) ---------
#define F4_C1   524288
#define F4_C2   1048576
#define F4_C3   2097152
#define F4_C4   2146304
#define F4_C5   2179072
#define F4_C6   2703360
__global__ __launch_bounds__(256) void f2bf_all_kernel(
    const float* __restrict__ W1, const float* __restrict__ W2,
    const float* __restrict__ inpj, const float* __restrict__ xpj,
    const float* __restrict__ dtpj, const float* __restrict__ outpj,
    unsigned short* __restrict__ o_w1, unsigned short* __restrict__ o_w2,
    unsigned short* __restrict__ o_in, unsigned short* __restrict__ o_xp,
    unsigned short* __restrict__ o_dt, unsigned short* __restrict__ o_out,
    unsigned int* __restrict__ gma)
{
    int i = blockIdx.x * 256 + threadIdx.x;
    if (blockIdx.x == 0 && threadIdx.x < 4) gma[threadIdx.x] = 0u;  // gamma init
    if (i >= F4_C6) return;
    const float* src; unsigned short* dst; int off; bool sign = false;
    if (i < F4_C1)      { src = W1;   dst = o_w1;  off = i;          sign = true; }
    else if (i < F4_C2) { src = W2;   dst = o_w2;  off = i - F4_C1;  sign = true; }
    else if (i < F4_C3) { src = inpj; dst = o_in;  off = i - F4_C2; }
    else if (i < F4_C4) { src = xpj;  dst = o_xp;  off = i - F4_C3; }
    else if (i < F4_C5) { src = dtpj; dst = o_dt;  off = i - F4_C4; }
    else                { src = outpj;dst = o_out; off = i - F4_C5; }
    float4 v = reinterpret_cast<const float4*>(src)[off];
    if (sign) { v.x = sgnf(v.x); v.y = sgnf(v.y); v.z = sgnf(v.z); v.w = sgnf(v.w); }
    ushort4 o;
    o.x = f2bf(v.x); o.y = f2bf(v.y); o.z = f2bf(v.z); o.w = f2bf(v.w);
    reinterpret_cast<ushort4*>(dst)[off] = o;
}

// ----------------------------- LN1 -> hi/lo bf16 ----------------------------
__global__ __launch_bounds__(256) void ln_hilo_kernel(const float* __restrict__ x,
                                                      const float* __restrict__ g,
                                                      const float* __restrict__ b,
                                                      unsigned short* __restrict__ hi,
                                                      unsigned short* __restrict__ lo) {
    int row = blockIdx.x, tid = threadIdx.x;
    float4 v = reinterpret_cast<const float4*>(x + (size_t)row * D_MODEL)[tid];
    float s = v.x + v.y + v.z + v.w;
    float q = v.x*v.x + v.y*v.y + v.z*v.z + v.w*v.w;
    #pragma unroll
    for (int off = 32; off > 0; off >>= 1) { s += __shfl_down(s, off); q += __shfl_down(q, off); }
    __shared__ float rs[4], rq[4], smean, srstd;
    if ((tid & 63) == 0) { rs[tid >> 6] = s; rq[tid >> 6] = q; }
    __syncthreads();
    if (tid == 0) {
        float ts = rs[0]+rs[1]+rs[2]+rs[3], tq = rq[0]+rq[1]+rq[2]+rq[3];
        float mean = ts * (1.0f / D_MODEL);
        smean = mean;
        srstd = rsqrtf(tq * (1.0f / D_MODEL) - mean*mean + EPS);
    }
    __syncthreads();
    float mean = smean, rstd = srstd;
    float4 gg = reinterpret_cast<const float4*>(g)[tid];
    float4 bb = reinterpret_cast<const float4*>(b)[tid];
    float o[4];
    o[0] = (v.x-mean)*rstd*gg.x + bb.x; o[1] = (v.y-mean)*rstd*gg.y + bb.y;
    o[2] = (v.z-mean)*rstd*gg.z + bb.z; o[3] = (v.w-mean)*rstd*gg.w + bb.w;
    ushort4 h4, l4;
    h4.x = f2bf(o[0]); l4.x = f2bf(o[0] - bf2f(h4.x));
    h4.y = f2bf(o[1]); l4.y = f2bf(o[1] - bf2f(h4.y));
    h4.z = f2bf(o[2]); l4.z = f2bf(o[2] - bf2f(h4.z));
    h4.w = f2bf(o[3]); l4.w = f2bf(o[3] - bf2f(h4.w));
    reinterpret_cast<ushort4*>(hi + (size_t)row * D_MODEL)[tid] = h4;
    reinterpret_cast<ushort4*>(lo + (size_t)row * D_MODEL)[tid] = l4;
}

// ----------------- 256x256 8-phase MFMA GEMM (bf16 out) ---------------------
// C[M,N]=A[M,K]@B[N,K]^T. 8 waves (2Mx4N), BK=64, 2-deep LDS double buffer,
// counted vmcnt(8) boundaries (wave-local stage queues), raw s_barrier phases.
// T2 XOR swizzle (rule #21): linear LDS dest, inverse-swizzled GLOBAL source
// (K-chunk lc^lr within each 128B row), swizzled ds_read (chunk c ^ (row&7)).
// Requires M%256==0, N%256==0, K%64==0, K/64>=2, grid (N/256, M/256), 512 thr.
__global__ __launch_bounds__(512) void mfma_gemm256_bf16out(
    const unsigned short* __restrict__ A, const unsigned short* __restrict__ B,
    unsigned short* __restrict__ Cb, int M, int N, int K, int sA, int sC)
{
    __shared__ __align__(16) unsigned short As[2][256*64];
    __shared__ __align__(16) unsigned short Bs[2][256*64];
    const int tid = threadIdx.x, lane = tid & 63, w = tid >> 6;
    const int wm = w >> 2, wn = w & 3;          // 2 x 4 wave grid
    int bx = blockIdx.x, by = blockIdx.y;
    {   // XCD-aware bijective swizzle (nwg % 8 == 0)
        const int gx = gridDim.x, nwg = gx * gridDim.y;
        int lin = by * gx + bx;
        int nl = (lin & 7) * (nwg >> 3) + (lin >> 3);
        bx = nl % gx; by = nl / gx;
    }
    const int row0 = by * 256, col0 = bx * 256;
    const int lr = lane >> 3, lc = lane & 7;     // stage: 8 rows x 8 chunks(16B)
    const int lcs = (lc ^ lr) << 3;              // pre-swizzled source elem off
    const int ga = wn;                           // group in A-half (wm)
    const int h2 = wn >> 1, g2 = wm * 2 + (wn & 1);  // B-half + group
    const int T = K >> 6;

    f32x4 acc[8][4];
    #pragma unroll
    for (int m = 0; m < 8; ++m)
        #pragma unroll
        for (int n = 0; n < 4; ++n) acc[m][n] = (f32x4){0.f,0.f,0.f,0.f};

    // wave stages ONLY the half-tiles it consumes: 4+4 instrs = its vmcnt queue
    auto STAGE = [&](int t) {
        const int kk = t << 6, p = t & 1;
        #pragma unroll
        for (int i = 0; i < 4; ++i) {
            const int rl = wm*128 + ga*32 + i*8;             // wave-uniform
            stage16(A + (size_t)(row0 + rl + lr) * sA + kk + lcs, &As[p][rl*64]);
        }
        #pragma unroll
        for (int i = 0; i < 4; ++i) {
            const int rl = h2*128 + g2*32 + i*8;
            stage16(B + (size_t)(col0 + rl + lr) * K + kk + lcs, &Bs[p][rl*64]);
        }
    };

    STAGE(0); STAGE(1);

    const int fr = lane & 15;
    const int sw = fr & 7;                        // row&7 for all frag rows
    const int q0 = (((lane >> 4)    ) ^ sw) << 3; // swz elem off, K-half 0
    const int q1 = (((lane >> 4) + 4) ^ sw) << 3; // swz elem off, K-half 1

    for (int t = 0; t < T; ++t) {
        const int p = t & 1;
        // boundary: my 8 loads for tile t landed (oldest); t+1's may fly on
        if (t + 1 < T) asm volatile("s_waitcnt vmcnt(8)" ::: "memory");
        else           asm volatile("s_waitcnt vmcnt(0)" ::: "memory");
        __builtin_amdgcn_sched_barrier(0);
        __builtin_amdgcn_s_barrier();            // broadcast: all waves waited

        const unsigned short* Ab = &As[p][(wm*128 + fr) * 64];
        const unsigned short* Bb = &Bs[p][(wn*64  + fr) * 64];
        short8v aX[4][2], bX[2][2], bY[2][2];

        // -- P1: read a0-3,b0-1; MFMA (m0-3)x(n0-1)
        #pragma unroll
        for (int m = 0; m < 4; ++m) {
            aX[m][0] = LDv(Ab + m*16*64 + q0);
            aX[m][1] = LDv(Ab + m*16*64 + q1);
        }
        #pragma unroll
        for (int n = 0; n < 2; ++n) {
            bX[n][0] = LDv(Bb + n*16*64 + q0);
            bX[n][1] = LDv(Bb + n*16*64 + q1);
        }
        __builtin_amdgcn_s_barrier();
        __builtin_amdgcn_s_setprio(1);
        #pragma unroll
        for (int m = 0; m < 4; ++m)
            #pragma unroll
            for (int n = 0; n < 2; ++n) {
                acc[m][n] = __builtin_amdgcn_mfma_f32_16x16x32_bf16(aX[m][0], bX[n][0], acc[m][n],0,0,0);
                acc[m][n] = __builtin_amdgcn_mfma_f32_16x16x32_bf16(aX[m][1], bX[n][1], acc[m][n],0,0,0);
            }
        __builtin_amdgcn_s_setprio(0);
        __builtin_amdgcn_s_barrier();
        // -- P2: read b2-3; MFMA (m0-3)x(n2-3)
        #pragma unroll
        for (int n = 0; n < 2; ++n) {
            bY[n][0] = LDv(Bb + (n+2)*16*64 + q0);
            bY[n][1] = LDv(Bb + (n+2)*16*64 + q1);
        }
        __builtin_amdgcn_s_barrier();
        __builtin_amdgcn_s_setprio(1);
        #pragma unroll
        for (int m = 0; m < 4; ++m)
            #pragma unroll
            for (int n = 0; n < 2; ++n) {
                acc[m][n+2] = __builtin_amdgcn_mfma_f32_16x16x32_bf16(aX[m][0], bY[n][0], acc[m][n+2],0,0,0);
                acc[m][n+2] = __builtin_amdgcn_mfma_f32_16x16x32_bf16(aX[m][1], bY[n][1], acc[m][n+2],0,0,0);
            }
        __builtin_amdgcn_s_setprio(0);
        __builtin_amdgcn_s_barrier();
        // -- P3: read a4-7 (reuse regs); MFMA (m4-7)x(n0-1)
        #pragma unroll
        for (int m = 0; m < 4; ++m) {
            aX[m][0] = LDv(Ab + (m+4)*16*64 + q0);
            aX[m][1] = LDv(Ab + (m+4)*16*64 + q1);
        }
        __builtin_amdgcn_s_barrier();
        __builtin_amdgcn_s_setprio(1);
        #pragma unroll
        for (int m = 0; m < 4; ++m)
            #pragma unroll
            for (int n = 0; n < 2; ++n) {
                acc[m+4][n] = __builtin_amdgcn_mfma_f32_16x16x32_bf16(aX[m][0], bX[n][0], acc[m+4][n],0,0,0);
                acc[m+4][n] = __builtin_amdgcn_mfma_f32_16x16x32_bf16(aX[m][1], bX[n][1], acc[m+4][n],0,0,0);
            }
        __builtin_amdgcn_s_setprio(0);
        __builtin_amdgcn_s_barrier();
        // -- P4: stage tile t+2 (buf p is free: all reads done by P3); MFMA (m4-7)x(n2-3)
        if (t + 2 < T) STAGE(t + 2);
        __builtin_amdgcn_s_barrier();
        __builtin_amdgcn_s_setprio(1);
        #pragma unroll
        for (int m = 0; m < 4; ++m)
            #pragma unroll
            for (int n = 0; n < 2; ++n) {
                acc[m+4][n+2] = __builtin_amdgcn_mfma_f32_16x16x32_bf16(aX[m][0], bY[n][0], acc[m+4][n+2],0,0,0);
                acc[m+4][n+2] = __builtin_amdgcn_mfma_f32_16x16x32_bf16(aX[m][1], bY[n][1], acc[m+4][n+2],0,0,0);
            }
        __builtin_amdgcn_s_setprio(0);
        __builtin_amdgcn_s_barrier();
    }

    // epilogue: C/D layout col=lane&15, row=(lane>>4)*4+reg
    const int fc = lane & 15, r4 = (lane >> 4) * 4;
    #pragma unroll
    for (int m = 0; m < 8; ++m) {
        const int r = row0 + wm*128 + m*16 + r4;
        #pragma unroll
        for (int n = 0; n < 4; ++n) {
            const int gc = col0 + wn*64 + n*16 + fc;
            #pragma unroll
            for (int j = 0; j < 4; ++j)
                Cb[(size_t)(r + j)*sC + gc] = f2bf(acc[m][n][j]);
        }
    }
}

// ----------------------------- MFMA GEMM (m97 128-tile) ---------------------
// EP: 0 C=fp32 | 1 Cb=bf16 clip(v+bias) | 3 Cb=bf16 softplus(v+bias)
template<int EP, bool DUALA, int BN, bool KSPLIT>
__global__ __launch_bounds__(256) void mfma_gemm(
    const unsigned short* __restrict__ A, const unsigned short* __restrict__ A2,
    const unsigned short* __restrict__ B, float* __restrict__ C,
    unsigned short* __restrict__ Cb,
    int M, int N, int K, int sA, int sC,
    const float* __restrict__ bias, int ksl)
{
    constexpr int NF = BN / 32;            // N-frags per wave (wave N-span BN/2)
    __shared__ __align__(16) unsigned short As[128*32];
    __shared__ __align__(16) unsigned short As2[DUALA ? 128*32 : 8];
    __shared__ __align__(16) unsigned short Bs[BN*32];
    const int tid = threadIdx.x;
    const int lane = tid & 63;
    const int w = tid >> 6;
    const int wm = w >> 1, wn = w & 1;

    int bx = blockIdx.x, by = blockIdx.y;
    if (!KSPLIT) {                          // XCD-aware bijective swizzle (nwg%8==0)
        const int gx = gridDim.x;
        const int nwg = gx * gridDim.y;
        int lin = by * gx + bx;
        int nl = (lin & 7) * (nwg >> 3) + (lin >> 3);
        bx = nl % gx; by = nl / gx;
    }
    const int row0 = by * 128, col0 = bx * BN;
    const int srow = lane >> 2;            // 0..15
    const int scol = (lane & 3) * 8;       // 0,8,16,24

    int k_begin = 0, k_end = K;
    if (KSPLIT) {
        int z = blockIdx.z;
        k_begin = z * ksl; k_end = k_begin + ksl;
        C += (size_t)z * M * sC;
    }

    f32x4 acc[4][NF];
    #pragma unroll
    for (int m = 0; m < 4; ++m)
        #pragma unroll
        for (int n = 0; n < NF; ++n)
            acc[m][n] = (f32x4){0.f, 0.f, 0.f, 0.f};

    for (int k0 = k_begin; k0 < k_end; k0 += 32) {
        #pragma unroll
        for (int i = 0; i < 2; ++i) {
            const int rbase = w * 32 + i * 16;               // wave-uniform
            stage16(A + (size_t)(row0 + rbase + srow) * sA + k0 + scol, &As[rbase * 32]);
            if (DUALA)
                stage16(A2 + (size_t)(row0 + rbase + srow) * sA + k0 + scol, &As2[rbase * 32]);
        }
        #pragma unroll
        for (int i = 0; i < BN/64; ++i) {
            const int rbase = (BN == 128) ? (w * 32 + i * 16) : (w * 16);
            if (col0 + rbase < N)                            // N%16==0 in all uses
                stage16(B + (size_t)(col0 + rbase + srow) * K + k0 + scol, &Bs[rbase * 32]);
        }
        __syncthreads();                                     // drains vmcnt before LDS reads

        short8v af[4], bfr[NF], af2[4];
        const int fr = lane & 15, kg = (lane >> 4) * 8;
        #pragma unroll
        for (int m = 0; m < 4; ++m)
            af[m] = *reinterpret_cast<const short8v*>(&As[(wm*64 + m*16 + fr) * 32 + kg]);
        if (DUALA) {
            #pragma unroll
            for (int m = 0; m < 4; ++m)
                af2[m] = *reinterpret_cast<const short8v*>(&As2[(wm*64 + m*16 + fr) * 32 + kg]);
        }
        #pragma unroll
        for (int n = 0; n < NF; ++n)
            bfr[n] = *reinterpret_cast<const short8v*>(&Bs[(wn*(BN/2) + n*16 + fr) * 32 + kg]);

        #pragma unroll
        for (int m = 0; m < 4; ++m)
            #pragma unroll
            for (int n = 0; n < NF; ++n) {
                acc[m][n] = __builtin_amdgcn_mfma_f32_16x16x32_bf16(af[m], bfr[n], acc[m][n], 0, 0, 0);
                if (DUALA)
                    acc[m][n] = __builtin_amdgcn_mfma_f32_16x16x32_bf16(af2[m], bfr[n], acc[m][n], 0, 0, 0);
            }
        __syncthreads();
    }

    // C/D layout (m89-verified): col = lane&15, row = (lane>>4)*4 + reg
    const int fc = lane & 15, r4 = (lane >> 4) * 4;
    #pragma unroll
    for (int m = 0; m < 4; ++m) {
        const int grb = row0 + wm*64 + m*16 + r4;
        #pragma unroll
        for (int n = 0; n < NF; ++n) {
            const int gc = col0 + wn*(BN/2) + n*16 + fc;
            if (gc >= N) continue;
            #pragma unroll
            for (int j = 0; j < 4; ++j) {
                const int r = grb + j;
                float v = acc[m][n][j];
                if (EP == 0) {
                    C[(size_t)r*sC + gc] = v;
                } else if (EP == 1) {
                    v += bias[gc];
                    v = fminf(1.0f, fmaxf(-1.0f, v));
                    Cb[(size_t)r*sC + gc] = f2bf(v);
                } else if (EP == 3) {
                    float t = v + bias[gc];
                    t = fmaxf(t, 0.0f) + log1pf(__expf(-fabsf(t)));
                    Cb[(size_t)r*sC + gc] = f2bf(t);
                }
            }
        }
    }
}

// -------- split-K combine: C = sum4(part) (+bias) + addx (+absmax->gma) -----
// one row (1024 cols) per block; part = [4][NTOK][1024] fp32
template<bool ABSMAX>
__global__ __launch_bounds__(256) void splitk_combine_kernel(
    const float* __restrict__ part, const float* __restrict__ bias,
    const float* __restrict__ addx, float* __restrict__ C,
    unsigned int* __restrict__ gma)
{
    const int row = blockIdx.x, tid = threadIdx.x;
    const size_t stride = (size_t)NTOK * D_MODEL / 4;
    const size_t i = (size_t)row * 256 + tid;
    float4 v0 = reinterpret_cast<const float4*>(part)[i];
    float4 v1 = reinterpret_cast<const float4*>(part)[i + stride];
    float4 v2 = reinterpret_cast<const float4*>(part)[i + 2*stride];
    float4 v3 = reinterpret_cast<const float4*>(part)[i + 3*stride];
    float4 ax = reinterpret_cast<const float4*>(addx)[i];
    float4 o;
    o.x = (v0.x + v1.x) + (v2.x + v3.x) + ax.x;
    o.y = (v0.y + v1.y) + (v2.y + v3.y) + ax.y;
    o.z = (v0.z + v1.z) + (v2.z + v3.z) + ax.z;
    o.w = (v0.w + v1.w) + (v2.w + v3.w) + ax.w;
    if (bias) {
        float4 b4 = reinterpret_cast<const float4*>(bias)[tid];
        o.x += b4.x; o.y += b4.y; o.z += b4.z; o.w += b4.w;
    }
    reinterpret_cast<float4*>(C)[i] = o;
    if (ABSMAX) {
        float m = fmaxf(fmaxf(fabsf(o.x), fabsf(o.y)), fmaxf(fabsf(o.z), fabsf(o.w)));
        #pragma unroll
        for (int off = 32; off > 0; off >>= 1) m = fmaxf(m, __shfl_down(m, off));
        __shared__ float red[4];
        if ((tid & 63) == 0) red[tid >> 6] = m;
        __syncthreads();
        if (tid == 0) {
            float t = fmaxf(fmaxf(red[0], red[1]), fmaxf(red[2], red[3]));
            atomicMax(gma + ((row & (SEQ - 1)) >> 9), __float_as_uint(t));
        }
    }
}

// ------------- x_proj split-K combine: xdbl = sum partials; emit bf16 dt ----
__global__ __launch_bounds__(256) void xproj_combine_kernel(
    const float* __restrict__ part,     // [4][NTOK][96]
    float* __restrict__ xdbl,           // [NTOK][96]
    unsigned short* __restrict__ xdt)   // [NTOK][64]
{
    int i = blockIdx.x * 256 + threadIdx.x;          // f4 index, NTOK*24 total
    if (i >= NTOK * 24) return;
    const size_t stride = (size_t)NTOK * 96 / 4;
    float4 v0 = reinterpret_cast<const float4*>(part)[i];
    float4 v1 = reinterpret_cast<const float4*>(part)[i + stride];
    float4 v2 = reinterpret_cast<const float4*>(part)[i + 2*stride];
    float4 v3 = reinterpret_cast<const float4*>(part)[i + 3*stride];
    float4 o;
    o.x = (v0.x + v1.x) + (v2.x + v3.x);
    o.y = (v0.y + v1.y) + (v2.y + v3.y);
    o.z = (v0.z + v1.z) + (v2.z + v3.z);
    o.w = (v0.w + v1.w) + (v2.w + v3.w);
    reinterpret_cast<float4*>(xdbl)[i] = o;
    int row = i / 24, c4 = i % 24;
    if (c4 < 16) {                                    // cols 0..63 -> bf16 dt input
        ushort4 u;
        u.x = f2bf(o.x); u.y = f2bf(o.y); u.z = f2bf(o.z); u.w = f2bf(o.w);
        reinterpret_cast<ushort4*>(xdt + (size_t)row * 64)[c4] = u;
    }
}

// ------------------- fused quant + LN2 (qx fp32 + u bf16) -------------------
__global__ __launch_bounds__(256) void quant_ln_kernel(
    const float* __restrict__ x2, const unsigned int* __restrict__ gamma_bits,
    const float* __restrict__ g, const float* __restrict__ b,
    float* __restrict__ qx, unsigned short* __restrict__ u)
{
    int row = blockIdx.x, tid = threadIdx.x;
    int grp = (row & (SEQ - 1)) >> 9;
    float gamma = __uint_as_float(gamma_bits[grp]);
    float scale = 128.0f / (gamma + EPS);
    const float lo = -128.0f + EPS, hi = 128.0f - EPS;
    float4 v = reinterpret_cast<const float4*>(x2 + (size_t)row * D_MODEL)[tid];
    float4 qv;
    qv.x = fminf(hi, fmaxf(lo, v.x * scale));
    qv.y = fminf(hi, fmaxf(lo, v.y * scale));
    qv.z = fminf(hi, fmaxf(lo, v.z * scale));
    qv.w = fminf(hi, fmaxf(lo, v.w * scale));
    reinterpret_cast<float4*>(qx + (size_t)row * D_MODEL)[tid] = qv;
    float s = qv.x + qv.y + qv.z + qv.w;
    float q = qv.x*qv.x + qv.y*qv.y + qv.z*qv.z + qv.w*qv.w;
    #pragma unroll
    for (int off = 32; off > 0; off >>= 1) { s += __shfl_down(s, off); q += __shfl_down(q, off); }
    __shared__ float rs[4], rq[4], smean, srstd;
    if ((tid & 63) == 0) { rs[tid >> 6] = s; rq[tid >> 6] = q; }
    __syncthreads();
    if (tid == 0) {
        float ts = rs[0]+rs[1]+rs[2]+rs[3], tq = rq[0]+rq[1]+rq[2]+rq[3];
        float mean = ts * (1.0f / D_MODEL);
        smean = mean;
        srstd = rsqrtf(tq * (1.0f / D_MODEL) - mean*mean + EPS);
    }
    __syncthreads();
    float mean = smean, rstd = srstd;
    float4 gg = reinterpret_cast<const float4*>(g)[tid];
    float4 bb = reinterpret_cast<const float4*>(b)[tid];
    ushort4 o;
    o.x = f2bf((qv.x-mean)*rstd*gg.x + bb.x);
    o.y = f2bf((qv.y-mean)*rstd*gg.y + bb.y);
    o.z = f2bf((qv.z-mean)*rstd*gg.z + bb.z);
    o.w = f2bf((qv.w-mean)*rstd*gg.w + bb.w);
    reinterpret_cast<ushort4*>(u + (size_t)row * D_MODEL)[tid] = o;
}

// -------------- depthwise causal conv + SiLU (bf16 in/out) ------------------
__global__ __launch_bounds__(256) void conv_silu_kernel(const unsigned short* __restrict__ xz,
                                                        const float* __restrict__ conv_w,
                                                        const float* __restrict__ conv_b,
                                                        unsigned short* __restrict__ xcb) {
    int c = blockIdx.x * 256 + threadIdx.x;   // 0..2047
    int m = blockIdx.y;                        // 0..4095
    int b = m >> 11, l = m & (SEQ - 1);
    float4 w4 = reinterpret_cast<const float4*>(conv_w)[c];
    float wv[4] = {w4.x, w4.y, w4.z, w4.w};
    float s = conv_b[c];
    const unsigned short* base = xz + ((size_t)b * SEQ) * 4096 + c;
    #pragma unroll
    for (int k = 0; k < 4; ++k) {
        int ll = l - 3 + k;
        if (ll >= 0) s += bf2f(base[(size_t)ll * 4096]) * wv[k];
    }
    float sig = 1.0f / (1.0f + __expf(-s));
    xcb[(size_t)m * D_INNER + c] = f2bf(s * sig);
}

// ----------------------------- chunked selective scan ------------------------
__device__ __forceinline__ void make_dA(float dA[D_STATE], float dtv,
                                        const float* a, bool pw) {
    if (pw) {
        dA[0] = __expf(dtv * a[0]);
        #pragma unroll
        for (int s = 1; s < D_STATE; ++s) dA[s] = dA[s>>1] * dA[(s-1)>>1];
    } else {
        #pragma unroll
        for (int s = 0; s < D_STATE; ++s) dA[s] = __expf(dtv * a[s]);
    }
}

__global__ __launch_bounds__(256) void scan_partial_kernel(
    const unsigned short* __restrict__ dt, const unsigned short* __restrict__ xcb,
    const float* __restrict__ xdbl, const float* __restrict__ A_log,
    float* __restrict__ Lbuf, float* __restrict__ Sbuf)
{
    int gtid = blockIdx.x * 256 + threadIdx.x;
    int ch = gtid & (NCH - 1);
    int c  = gtid >> 12;                      // chunk 0..63
    int b = ch >> 11, d = ch & (D_INNER - 1);
    float a[D_STATE], h[D_STATE];
    bool pw = true;
    #pragma unroll
    for (int s = 0; s < D_STATE; ++s) {
        a[s] = -__expf(A_log[(size_t)d * D_STATE + s]);
        h[s] = 0.0f;
    }
    #pragma unroll
    for (int s = 1; s < D_STATE; ++s)
        pw = pw && (fabsf(a[s] - a[0]*(float)(s+1)) <= 1e-3f * fabsf(a[s]));

    size_t m0 = (size_t)b * SEQ + (size_t)c * CLEN;
    float Ssum = 0.0f;

    float dt_n = bf2f(dt[m0 * D_INNER + d]);
    float x_n  = bf2f(xcb[m0 * D_INNER + d]);
    float4 B_n[4];
    {
        const float* xd = xdbl + m0 * 96;
        #pragma unroll
        for (int i = 0; i < 4; ++i)
            B_n[i] = *reinterpret_cast<const float4*>(xd + DT_RANK + 4*i);
    }

    for (int l = 0; l < CLEN; ++l) {
        float dtv = dt_n, xv = x_n;
        float Bc[D_STATE];
        #pragma unroll
        for (int i = 0; i < 4; ++i) {
            Bc[4*i+0] = B_n[i].x; Bc[4*i+1] = B_n[i].y; Bc[4*i+2] = B_n[i].z; Bc[4*i+3] = B_n[i].w;
        }
        if (l + 1 < CLEN) {
            size_t m1 = m0 + l + 1;
            dt_n = bf2f(dt[m1 * D_INNER + d]);
            x_n  = bf2f(xcb[m1 * D_INNER + d]);
            const float* xd = xdbl + m1 * 96;
            #pragma unroll
            for (int i = 0; i < 4; ++i)
                B_n[i] = *reinterpret_cast<const float4*>(xd + DT_RANK + 4*i);
        }
        Ssum += dtv;
        float dx = dtv * xv;
        float dA[D_STATE];
        make_dA(dA, dtv, a, pw);
        #pragma unroll
        for (int s = 0; s < D_STATE; ++s)
            h[s] = h[s] * dA[s] + dx * Bc[s];
    }
    float4* Lp = reinterpret_cast<float4*>(Lbuf + (size_t)c * (NCH * D_STATE) + (size_t)ch * D_STATE);
    Lp[0] = make_float4(h[0], h[1], h[2], h[3]);
    Lp[1] = make_float4(h[4], h[5], h[6], h[7]);
    Lp[2] = make_float4(h[8], h[9], h[10], h[11]);
    Lp[3] = make_float4(h[12], h[13], h[14], h[15]);
    Sbuf[(size_t)c * NCH + ch] = Ssum;
}

__global__ __launch_bounds__(256) void scan_combine_kernel(
    float* __restrict__ LH, const float* __restrict__ Sbuf,
    const float* __restrict__ A_log)
{
    int gtid = blockIdx.x * 256 + threadIdx.x;
    int s = gtid & (D_STATE - 1);
    int ch = gtid >> 4;
    int d = ch & (D_INNER - 1);
    float a = -__expf(A_log[(size_t)d * D_STATE + s]);
    float h = 0.0f;
    #pragma unroll 4
    for (int c = 0; c < NCHUNK; ++c) {
        size_t idx = (size_t)c * (NCH * D_STATE) + (size_t)ch * D_STATE + s;
        float loc = LH[idx];
        LH[idx] = h;
        float P = __expf(a * Sbuf[(size_t)c * NCH + ch]);
        h = h * P + loc;
    }
}

__global__ __launch_bounds__(256) void scan_final_kernel(
    const unsigned short* __restrict__ dt, const unsigned short* __restrict__ xcb,
    const unsigned short* __restrict__ xzb, const float* __restrict__ xdbl,
    const float* __restrict__ A_log, const float* __restrict__ D_param,
    const float* __restrict__ Hin, unsigned short* __restrict__ yb)
{
    int gtid = blockIdx.x * 256 + threadIdx.x;
    int ch = gtid & (NCH - 1);
    int c  = gtid >> 12;
    int b = ch >> 11, d = ch & (D_INNER - 1);
    float a[D_STATE], h[D_STATE];
    {
        const float4* Hp = reinterpret_cast<const float4*>(
            Hin + (size_t)c * (NCH * D_STATE) + (size_t)ch * D_STATE);
        float4 h0 = Hp[0], h1 = Hp[1], h2 = Hp[2], h3 = Hp[3];
        h[0]=h0.x; h[1]=h0.y; h[2]=h0.z; h[3]=h0.w;
        h[4]=h1.x; h[5]=h1.y; h[6]=h1.z; h[7]=h1.w;
        h[8]=h2.x; h[9]=h2.y; h[10]=h2.z; h[11]=h2.w;
        h[12]=h3.x; h[13]=h3.y; h[14]=h3.z; h[15]=h3.w;
    }
    bool pw = true;
    #pragma unroll
    for (int s = 0; s < D_STATE; ++s)
        a[s] = -__expf(A_log[(size_t)d * D_STATE + s]);
    #pragma unroll
    for (int s = 1; s < D_STATE; ++s)
        pw = pw && (fabsf(a[s] - a[0]*(float)(s+1)) <= 1e-3f * fabsf(a[s]));
    float Dp = D_param[d];

    size_t m0 = (size_t)b * SEQ + (size_t)c * CLEN;
    float dt_n = bf2f(dt[m0 * D_INNER + d]);
    float x_n  = bf2f(xcb[m0 * D_INNER + d]);
    float z_n  = bf2f(xzb[m0 * 4096 + D_INNER + d]);
    float4 B_n[4], C_n[4];
    {
        const float* xd = xdbl + m0 * 96;
        #pragma unroll
        for (int i = 0; i < 4; ++i) {
            B_n[i] = *reinterpret_cast<const float4*>(xd + DT_RANK + 4*i);
            C_n[i] = *reinterpret_cast<const float4*>(xd + DT_RANK + D_STATE + 4*i);
        }
    }

    for (int l = 0; l < CLEN; ++l) {
        float dtv = dt_n, xv = x_n, zv = z_n;
        float Bc[D_STATE], Cc[D_STATE];
        #pragma unroll
        for (int i = 0; i < 4; ++i) {
            Bc[4*i+0] = B_n[i].x; Bc[4*i+1] = B_n[i].y; Bc[4*i+2] = B_n[i].z; Bc[4*i+3] = B_n[i].w;
            Cc[4*i+0] = C_n[i].x; Cc[4*i+1] = C_n[i].y; Cc[4*i+2] = C_n[i].z; Cc[4*i+3] = C_n[i].w;
        }
        if (l + 1 < CLEN) {
            size_t m1 = m0 + l + 1;
            dt_n = bf2f(dt[m1 * D_INNER + d]);
            x_n  = bf2f(xcb[m1 * D_INNER + d]);
            z_n  = bf2f(xzb[m1 * 4096 + D_INNER + d]);
            const float* xd = xdbl + m1 * 96;
            #pragma unroll
            for (int i = 0; i < 4; ++i) {
                B_n[i] = *reinterpret_cast<const float4*>(xd + DT_RANK + 4*i);
                C_n[i] = *reinterpret_cast<const float4*>(xd + DT_RANK + D_STATE + 4*i);
            }
        }
        float dx = dtv * xv;
        float yv = 0.0f;
        float dA[D_STATE];
        make_dA(dA, dtv, a, pw);
        #pragma unroll
        for (int s = 0; s < D_STATE; ++s) {
            h[s] = h[s] * dA[s] + dx * Bc[s];
            yv += h[s] * Cc[s];
        }
        yv += Dp * xv;
        float sig = 1.0f / (1.0f + __expf(-zv));
        yb[(m0 + l) * D_INNER + d] = f2bf(yv * (zv * sig));
    }
}

// ----------------------------- launch ---------------------------------------
extern "C" void kernel_launch(void* const* d_in, const int* in_sizes, int n_in,
                              void* d_out, int out_size, void* d_ws, size_t ws_size,
                              hipStream_t stream) {
    const float* x         = (const float*)d_in[0];
    const float* ln1_g     = (const float*)d_in[1];
    const float* ln1_b     = (const float*)d_in[2];
    const float* ln2_g     = (const float*)d_in[3];
    const float* ln2_b     = (const float*)d_in[4];
    const float* W1        = (const float*)d_in[5];
    const float* b1        = (const float*)d_in[6];
    const float* W2        = (const float*)d_in[7];
    const float* b2        = (const float*)d_in[8];
    const float* in_proj   = (const float*)d_in[9];
    const float* conv_w    = (const float*)d_in[10];
    const float* conv_b    = (const float*)d_in[11];
    const float* x_proj    = (const float*)d_in[12];
    const float* dt_proj   = (const float*)d_in[13];
    const float* dt_proj_b = (const float*)d_in[14];
    const float* A_log     = (const float*)d_in[15];
    const float* D_param   = (const float*)d_in[16];
    const float* out_proj  = (const float*)d_in[17];
    float* out = (float*)d_out;

    // ---- workspace layout (bytes), ~159 MiB ----
    char* ws = (char*)d_ws;
    float*          f_x2   = (float*)         (ws + 0);          // 16,777,216  x2/qx
    unsigned short* b_xz   = (unsigned short*)(ws + 16777216);   // 33,554,432  bf16 [xs|z]
    unsigned short* b_dt   = (unsigned short*)(ws + 50331648);   // 16,777,216  dt bf16
    // split-K partial scratch: [16MB,80MB) — free at G2 time (b_xz/b_dt not yet
    // written) and at out_proj time (b_xz/b_dt fully consumed by scan_final)
    float*          f_p4   = (float*)         (ws + 16777216);   // 67,108,864
    float*          f_xdbl = (float*)         (ws + 83886080);   //  1,572,864
    float*          f_L    = (float*)         (ws + 85458944);   // 16,777,216  (scan L; earlier: xproj partials)
    float*          f_xp   = f_L;                                //  6,291,456  alias (consumed before scan)
    float*          f_S    = (float*)         (ws + 102236160);  //  1,048,576
    unsigned int*   f_gamma= (unsigned int*)  (ws + 103284736);  // 64
    unsigned short* b_a1hi = (unsigned short*)(ws + 103284800);  //  8,388,608
    unsigned short* b_a1lo = b_a1hi + 4194304;                   //  8,388,608
    unsigned short* b_y    = b_a1hi;                             //  reuse 16 MB
    unsigned short* b_gated= (unsigned short*)(ws + 120062016);  // 16,777,216
    unsigned short* b_xc   = b_gated;                            //  reuse
    unsigned short* b_u    = (unsigned short*)(ws + 136839232);  //  8,388,608
    unsigned short* b_xdt  = b_u;                                //  reuse 512 KB
    unsigned short* b_w1s  = (unsigned short*)(ws + 145227840);  //  4,194,304
    unsigned short* b_w2s  = (unsigned short*)(ws + 149422144);  //  4,194,304
    unsigned short* b_inpj = (unsigned short*)(ws + 153616448);  //  8,388,608
    unsigned short* b_xpj  = (unsigned short*)(ws + 162005056);  //    393,216
    unsigned short* b_dtpj = (unsigned short*)(ws + 162398272);  //    262,144
    unsigned short* b_outpj= (unsigned short*)(ws + 162660416);  //  4,194,304

    dim3 b256(256);

    // 0. all weight conversions (+ gamma init) in one launch
    f2bf_all_kernel<<<dim3((F4_C6 + 255)/256), b256, 0, stream>>>(
        W1, W2, in_proj, x_proj, dt_proj, out_proj,
        b_w1s, b_w2s, b_inpj, b_xpj, b_dtpj, b_outpj, f_gamma);

    // 1. LN1 -> hi/lo bf16
    ln_hilo_kernel<<<dim3(NTOK), b256, 0, stream>>>(x, ln1_g, ln1_b, b_a1hi, b_a1lo);
    // 2. gated = clip((hi+lo) @ sign(W1)^T + b1) -> bf16   [BN=128, 512 blocks]
    mfma_gemm<1, true, 128, false><<<dim3(16, 32), b256, 0, stream>>>(
        b_a1hi, b_a1lo, b_w1s, nullptr, b_gated, NTOK, D_INNER, D_MODEL, D_MODEL, D_INNER,
        b1, 0);
    // 3a. G2 partials = gated @ sign(W2)^T  [split-K x4, 1024 blocks]
    mfma_gemm<0, false, 128, true><<<dim3(8, 32, 4), b256, 0, stream>>>(
        b_gated, nullptr, b_w2s, f_p4, nullptr, NTOK, D_MODEL, D_INNER, D_INNER, D_MODEL,
        nullptr, 512);
    // 3b. x2 = sum + b2 + x -> fp32, absmax -> gamma
    splitk_combine_kernel<true><<<dim3(NTOK), b256, 0, stream>>>(f_p4, b2, x, f_x2, f_gamma);
    // 4+5. fused quant + LN2 -> qx fp32, u bf16
    quant_ln_kernel<<<dim3(NTOK), b256, 0, stream>>>(f_x2, f_gamma, ln2_g, ln2_b, f_x2, b_u);
    // 6. xz = u @ in_proj^T -> bf16   [256x256 8-phase + T2 swizzle, 256 blocks]
    mfma_gemm256_bf16out<<<dim3(16, 16), dim3(512), 0, stream>>>(
        b_u, b_inpj, b_xz, NTOK, 2*D_INNER, D_MODEL, D_MODEL, 2*D_INNER);
    // 7. conv + silu -> bf16 xc
    conv_silu_kernel<<<dim3(D_INNER/256, NTOK), b256, 0, stream>>>(b_xz, conv_w, conv_b, b_xc);
    // 8. x_dbl partials = xc @ x_proj^T  [split-K x4, 128 blocks]
    mfma_gemm<0, false, 128, true><<<dim3(1, 32, 4), b256, 0, stream>>>(
        b_xc, nullptr, b_xpj, f_xp, nullptr, NTOK, DT_RANK + 2*D_STATE, D_INNER, D_INNER,
        DT_RANK + 2*D_STATE, nullptr, 512);
    // 8b. combine partials -> f_xdbl fp32 + b_xdt bf16
    xproj_combine_kernel<<<dim3((NTOK*24 + 255)/256), b256, 0, stream>>>(f_xp, f_xdbl, b_xdt);
    // 9. dt = softplus(xdt @ dt_proj^T + b) -> bf16  [BN=64, 1024 blocks]
    mfma_gemm<3, false, 64, false><<<dim3(32, 32), b256, 0, stream>>>(
        b_xdt, nullptr, b_dtpj, nullptr, b_dt, NTOK, D_INNER, DT_RANK, DT_RANK, D_INNER,
        dt_proj_b, 0);
    // 10. chunked scan
    scan_partial_kernel<<<dim3(NCH*NCHUNK/256), b256, 0, stream>>>(
        b_dt, b_xc, f_xdbl, A_log, f_L, f_S);
    scan_combine_kernel<<<dim3(NCH*D_STATE/256), b256, 0, stream>>>(f_L, f_S, A_log);
    scan_final_kernel<<<dim3(NCH*NCHUNK/256), b256, 0, stream>>>(
        b_dt, b_xc, b_xz, f_xdbl, A_log, D_param, f_L, b_y);
    // 11a. out_proj partials = y @ out_proj^T  [split-K x4, 1024 blocks]
    mfma_gemm<0, false, 128, true><<<dim3(8, 32, 4), b256, 0, stream>>>(
        b_y, nullptr, b_outpj, f_p4, nullptr, NTOK, D_MODEL, D_INNER, D_INNER, D_MODEL,
        nullptr, 512);
    // 11b. out = sum + qx -> fp32
    splitk_combine_kernel<false><<<dim3(NTOK), b256, 0, stream>>>(f_p4, nullptr, f_x2, out, nullptr);
}

// Round 12
// 456.289 us; speedup vs baseline: 1.1384x; 1.1384x over previous
//
#include <hip/hip_runtime.h>
#include <math.h>

#define D_MODEL 1024
#define D_INNER 2048
#define D_STATE 16
#define DT_RANK 64
#define BSZ 2
#define SEQ 2048
#define NTOK (BSZ*SEQ)     // 4096
#define NCH  (BSZ*D_INNER) // 4096 channels
#define NCHUNK 64
#define CLEN 32            // SEQ / NCHUNK
#define EPS 1e-5f

typedef __attribute__((ext_vector_type(8))) short short8v;
typedef __attribute__((ext_vector_type(4))) float f32x4;

__device__ __forceinline__ float sgnf(float w) {
    return (w > 0.f) ? 1.f : ((w < 0.f) ? -1.f : 0.f);
}
__device__ __forceinline__ unsigned short f2bf(float f) {   // RNE fp32->bf16
    unsigned int x = __float_as_uint(f);
    x += 0x7fffu + ((x >> 16) & 1u);
    return (unsigned short)(x >> 16);
}
__device__ __forceinline__ float bf2f(unsigned short u) {
    return __uint_as_float(((unsigned int)u) << 16);
}
__device__ __forceinline__ void stage16(const unsigned short* g, unsigned short* l) {
    __builtin_amdgcn_global_load_lds(
        (const __attribute__((address_space(1))) unsigned int*)g,
        (__attribute__((address_space(3))) unsigned int*)l, 16, 0, 0);
}
#define LDv(p) (*reinterpret_cast<const short8v*>(p))

// ------------------- merged weight conversion (6 tensors, 1 launch) ---------
#define F4_C1   524288
#define F4_C2   1048576
#define F4_C3   2097152
#define F4_C4   2146304
#define F4_C5   2179072
#define F4_C6   2703360
__global__ __launch_bounds__(256) void f2bf_all_kernel(
    const float* __restrict__ W1, const float* __restrict__ W2,
    const float* __restrict__ inpj, const float* __restrict__ xpj,
    const float* __restrict__ dtpj, const float* __restrict__ outpj,
    unsigned short* __restrict__ o_w1, unsigned short* __restrict__ o_w2,
    unsigned short* __restrict__ o_in, unsigned short* __restrict__ o_xp,
    unsigned short* __restrict__ o_dt, unsigned short* __restrict__ o_out,
    unsigned int* __restrict__ gma)
{
    int i = blockIdx.x * 256 + threadIdx.x;
    if (blockIdx.x == 0 && threadIdx.x < 4) gma[threadIdx.x] = 0u;  // gamma init
    if (i >= F4_C6) return;
    const float* src; unsigned short* dst; int off; bool sign = false;
    if (i < F4_C1)      { src = W1;   dst = o_w1;  off = i;          sign = true; }
    else if (i < F4_C2) { src = W2;   dst = o_w2;  off = i - F4_C1;  sign = true; }
    else if (i < F4_C3) { src = inpj; dst = o_in;  off = i - F4_C2; }
    else if (i < F4_C4) { src = xpj;  dst = o_xp;  off = i - F4_C3; }
    else if (i < F4_C5) { src = dtpj; dst = o_dt;  off = i - F4_C4; }
    else                { src = outpj;dst = o_out; off = i - F4_C5; }
    float4 v = reinterpret_cast<const float4*>(src)[off];
    if (sign) { v.x = sgnf(v.x); v.y = sgnf(v.y); v.z = sgnf(v.z); v.w = sgnf(v.w); }
    ushort4 o;
    o.x = f2bf(v.x); o.y = f2bf(v.y); o.z = f2bf(v.z); o.w = f2bf(v.w);
    reinterpret_cast<ushort4*>(dst)[off] = o;
}

// ----------------------------- LN1 -> hi/lo bf16 ----------------------------
__global__ __launch_bounds__(256) void ln_hilo_kernel(const float* __restrict__ x,
                                                      const float* __restrict__ g,
                                                      const float* __restrict__ b,
                                                      unsigned short* __restrict__ hi,
                                                      unsigned short* __restrict__ lo) {
    int row = blockIdx.x, tid = threadIdx.x;
    float4 v = reinterpret_cast<const float4*>(x + (size_t)row * D_MODEL)[tid];
    float s = v.x + v.y + v.z + v.w;
    float q = v.x*v.x + v.y*v.y + v.z*v.z + v.w*v.w;
    #pragma unroll
    for (int off = 32; off > 0; off >>= 1) { s += __shfl_down(s, off); q += __shfl_down(q, off); }
    __shared__ float rs[4], rq[4], smean, srstd;
    if ((tid & 63) == 0) { rs[tid >> 6] = s; rq[tid >> 6] = q; }
    __syncthreads();
    if (tid == 0) {
        float ts = rs[0]+rs[1]+rs[2]+rs[3], tq = rq[0]+rq[1]+rq[2]+rq[3];
        float mean = ts * (1.0f / D_MODEL);
        smean = mean;
        srstd = rsqrtf(tq * (1.0f / D_MODEL) - mean*mean + EPS);
    }
    __syncthreads();
    float mean = smean, rstd = srstd;
    float4 gg = reinterpret_cast<const float4*>(g)[tid];
    float4 bb = reinterpret_cast<const float4*>(b)[tid];
    float o[4];
    o[0] = (v.x-mean)*rstd*gg.x + bb.x; o[1] = (v.y-mean)*rstd*gg.y + bb.y;
    o[2] = (v.z-mean)*rstd*gg.z + bb.z; o[3] = (v.w-mean)*rstd*gg.w + bb.w;
    ushort4 h4, l4;
    h4.x = f2bf(o[0]); l4.x = f2bf(o[0] - bf2f(h4.x));
    h4.y = f2bf(o[1]); l4.y = f2bf(o[1] - bf2f(h4.y));
    h4.z = f2bf(o[2]); l4.z = f2bf(o[2] - bf2f(h4.z));
    h4.w = f2bf(o[3]); l4.w = f2bf(o[3] - bf2f(h4.w));
    reinterpret_cast<ushort4*>(hi + (size_t)row * D_MODEL)[tid] = h4;
    reinterpret_cast<ushort4*>(lo + (size_t)row * D_MODEL)[tid] = l4;
}

// ----------------- 256x256 8-phase MFMA GEMM (bf16 out) ---------------------
// Validated r9/r10. T2 XOR swizzle: linear LDS dest, inverse-swizzled global
// source, swizzled ds_read. Counted vmcnt(8) boundaries, raw s_barrier phases.
__global__ __launch_bounds__(512) void mfma_gemm256_bf16out(
    const unsigned short* __restrict__ A, const unsigned short* __restrict__ B,
    unsigned short* __restrict__ Cb, int M, int N, int K, int sA, int sC)
{
    __shared__ __align__(16) unsigned short As[2][256*64];
    __shared__ __align__(16) unsigned short Bs[2][256*64];
    const int tid = threadIdx.x, lane = tid & 63, w = tid >> 6;
    const int wm = w >> 2, wn = w & 3;          // 2 x 4 wave grid
    int bx = blockIdx.x, by = blockIdx.y;
    {   // XCD-aware bijective swizzle (nwg % 8 == 0)
        const int gx = gridDim.x, nwg = gx * gridDim.y;
        int lin = by * gx + bx;
        int nl = (lin & 7) * (nwg >> 3) + (lin >> 3);
        bx = nl % gx; by = nl / gx;
    }
    const int row0 = by * 256, col0 = bx * 256;
    const int lr = lane >> 3, lc = lane & 7;     // stage: 8 rows x 8 chunks(16B)
    const int lcs = (lc ^ lr) << 3;              // pre-swizzled source elem off
    const int ga = wn;
    const int h2 = wn >> 1, g2 = wm * 2 + (wn & 1);
    const int T = K >> 6;

    f32x4 acc[8][4];
    #pragma unroll
    for (int m = 0; m < 8; ++m)
        #pragma unroll
        for (int n = 0; n < 4; ++n) acc[m][n] = (f32x4){0.f,0.f,0.f,0.f};

    auto STAGE = [&](int t) {
        const int kk = t << 6, p = t & 1;
        #pragma unroll
        for (int i = 0; i < 4; ++i) {
            const int rl = wm*128 + ga*32 + i*8;
            stage16(A + (size_t)(row0 + rl + lr) * sA + kk + lcs, &As[p][rl*64]);
        }
        #pragma unroll
        for (int i = 0; i < 4; ++i) {
            const int rl = h2*128 + g2*32 + i*8;
            stage16(B + (size_t)(col0 + rl + lr) * K + kk + lcs, &Bs[p][rl*64]);
        }
    };

    STAGE(0); STAGE(1);

    const int fr = lane & 15;
    const int sw = fr & 7;
    const int q0 = (((lane >> 4)    ) ^ sw) << 3;
    const int q1 = (((lane >> 4) + 4) ^ sw) << 3;

    for (int t = 0; t < T; ++t) {
        const int p = t & 1;
        if (t + 1 < T) asm volatile("s_waitcnt vmcnt(8)" ::: "memory");
        else           asm volatile("s_waitcnt vmcnt(0)" ::: "memory");
        __builtin_amdgcn_sched_barrier(0);
        __builtin_amdgcn_s_barrier();

        const unsigned short* Ab = &As[p][(wm*128 + fr) * 64];
        const unsigned short* Bb = &Bs[p][(wn*64  + fr) * 64];
        short8v aX[4][2], bX[2][2], bY[2][2];

        // -- P1
        #pragma unroll
        for (int m = 0; m < 4; ++m) {
            aX[m][0] = LDv(Ab + m*16*64 + q0);
            aX[m][1] = LDv(Ab + m*16*64 + q1);
        }
        #pragma unroll
        for (int n = 0; n < 2; ++n) {
            bX[n][0] = LDv(Bb + n*16*64 + q0);
            bX[n][1] = LDv(Bb + n*16*64 + q1);
        }
        __builtin_amdgcn_s_barrier();
        __builtin_amdgcn_s_setprio(1);
        #pragma unroll
        for (int m = 0; m < 4; ++m)
            #pragma unroll
            for (int n = 0; n < 2; ++n) {
                acc[m][n] = __builtin_amdgcn_mfma_f32_16x16x32_bf16(aX[m][0], bX[n][0], acc[m][n],0,0,0);
                acc[m][n] = __builtin_amdgcn_mfma_f32_16x16x32_bf16(aX[m][1], bX[n][1], acc[m][n],0,0,0);
            }
        __builtin_amdgcn_s_setprio(0);
        __builtin_amdgcn_s_barrier();
        // -- P2
        #pragma unroll
        for (int n = 0; n < 2; ++n) {
            bY[n][0] = LDv(Bb + (n+2)*16*64 + q0);
            bY[n][1] = LDv(Bb + (n+2)*16*64 + q1);
        }
        __builtin_amdgcn_s_barrier();
        __builtin_amdgcn_s_setprio(1);
        #pragma unroll
        for (int m = 0; m < 4; ++m)
            #pragma unroll
            for (int n = 0; n < 2; ++n) {
                acc[m][n+2] = __builtin_amdgcn_mfma_f32_16x16x32_bf16(aX[m][0], bY[n][0], acc[m][n+2],0,0,0);
                acc[m][n+2] = __builtin_amdgcn_mfma_f32_16x16x32_bf16(aX[m][1], bY[n][1], acc[m][n+2],0,0,0);
            }
        __builtin_amdgcn_s_setprio(0);
        __builtin_amdgcn_s_barrier();
        // -- P3
        #pragma unroll
        for (int m = 0; m < 4; ++m) {
            aX[m][0] = LDv(Ab + (m+4)*16*64 + q0);
            aX[m][1] = LDv(Ab + (m+4)*16*64 + q1);
        }
        __builtin_amdgcn_s_barrier();
        __builtin_amdgcn_s_setprio(1);
        #pragma unroll
        for (int m = 0; m < 4; ++m)
            #pragma unroll
            for (int n = 0; n < 2; ++n) {
                acc[m+4][n] = __builtin_amdgcn_mfma_f32_16x16x32_bf16(aX[m][0], bX[n][0], acc[m+4][n],0,0,0);
                acc[m+4][n] = __builtin_amdgcn_mfma_f32_16x16x32_bf16(aX[m][1], bX[n][1], acc[m+4][n],0,0,0);
            }
        __builtin_amdgcn_s_setprio(0);
        __builtin_amdgcn_s_barrier();
        // -- P4 (stage after ALL reads of buf p)
        if (t + 2 < T) STAGE(t + 2);
        __builtin_amdgcn_s_barrier();
        __builtin_amdgcn_s_setprio(1);
        #pragma unroll
        for (int m = 0; m < 4; ++m)
            #pragma unroll
            for (int n = 0; n < 2; ++n) {
                acc[m+4][n+2] = __builtin_amdgcn_mfma_f32_16x16x32_bf16(aX[m][0], bY[n][0], acc[m+4][n+2],0,0,0);
                acc[m+4][n+2] = __builtin_amdgcn_mfma_f32_16x16x32_bf16(aX[m][1], bY[n][1], acc[m+4][n+2],0,0,0);
            }
        __builtin_amdgcn_s_setprio(0);
        __builtin_amdgcn_s_barrier();
    }

    const int fc = lane & 15, r4 = (lane >> 4) * 4;
    #pragma unroll
    for (int m = 0; m < 8; ++m) {
        const int r = row0 + wm*128 + m*16 + r4;
        #pragma unroll
        for (int n = 0; n < 4; ++n) {
            const int gc = col0 + wn*64 + n*16 + fc;
            #pragma unroll
            for (int j = 0; j < 4; ++j)
                Cb[(size_t)(r + j)*sC + gc] = f2bf(acc[m][n][j]);
        }
    }
}

// ----------- 128x128 8-phase MFMA GEMM, fp32 out + epilogue -----------------
// Same pipeline discipline as the 256² template, spans halved. 8 waves (2Mx4N:
// wave 64 rows x 32 cols), BK=64, 64KB LDS dbuf, wave-local 4-load queues ->
// vmcnt(4) boundaries, 3 phases/tile (stage in P3, after all buf-p reads).
// EP: 7 = v+bias+addx, absmax->gma | 4 = v+addx
template<int EP>
__global__ __launch_bounds__(512) void mfma_gemm128_8ph(
    const unsigned short* __restrict__ A, const unsigned short* __restrict__ B,
    float* __restrict__ C, int M, int N, int K, int sA, int sC,
    const float* __restrict__ bias, const float* __restrict__ addx, int sAdd,
    unsigned int* __restrict__ gma)
{
    __shared__ __align__(16) unsigned short As[2][128*64];
    __shared__ __align__(16) unsigned short Bs[2][128*64];
    __shared__ float redmax[8];
    const int tid = threadIdx.x, lane = tid & 63, w = tid >> 6;
    const int wm = w >> 2, wn = w & 3;          // 2 x 4 wave grid
    int bx = blockIdx.x, by = blockIdx.y;
    {   // XCD-aware bijective swizzle (nwg % 8 == 0)
        const int gx = gridDim.x, nwg = gx * gridDim.y;
        int lin = by * gx + bx;
        int nl = (lin & 7) * (nwg >> 3) + (lin >> 3);
        bx = nl % gx; by = nl / gx;
    }
    const int row0 = by * 128, col0 = bx * 128;
    const int lr = lane >> 3, lc = lane & 7;
    const int lcs = (lc ^ lr) << 3;              // T2: pre-swizzled source
    const int T = K >> 6;

    f32x4 acc[4][2];
    #pragma unroll
    for (int m = 0; m < 4; ++m) {
        acc[m][0] = (f32x4){0.f,0.f,0.f,0.f};
        acc[m][1] = (f32x4){0.f,0.f,0.f,0.f};
    }

    // wave w stages A rows [w*16,w*16+16) and B rows [w*16,w*16+16): 4 loads
    auto STAGE = [&](int t) {
        const int kk = t << 6, p = t & 1;
        #pragma unroll
        for (int i = 0; i < 2; ++i) {
            const int rl = w*16 + i*8;
            stage16(A + (size_t)(row0 + rl + lr) * sA + kk + lcs, &As[p][rl*64]);
        }
        #pragma unroll
        for (int i = 0; i < 2; ++i) {
            const int rl = w*16 + i*8;
            stage16(B + (size_t)(col0 + rl + lr) * K + kk + lcs, &Bs[p][rl*64]);
        }
    };

    STAGE(0); STAGE(1);

    const int fr = lane & 15;
    const int sw = fr & 7;
    const int q0 = (((lane >> 4)    ) ^ sw) << 3;
    const int q1 = (((lane >> 4) + 4) ^ sw) << 3;

    for (int t = 0; t < T; ++t) {
        const int p = t & 1;
        if (t + 1 < T) asm volatile("s_waitcnt vmcnt(4)" ::: "memory");
        else           asm volatile("s_waitcnt vmcnt(0)" ::: "memory");
        __builtin_amdgcn_sched_barrier(0);
        __builtin_amdgcn_s_barrier();

        const unsigned short* Ab = &As[p][(wm*64 + fr) * 64];
        const unsigned short* Bb = &Bs[p][(wn*32 + fr) * 64];
        short8v aX[4][2], bX[2][2];

        // -- P1: read a0-1 (both k-halves) + b0-1; MFMA (m0-1)x(n0-1)
        #pragma unroll
        for (int m = 0; m < 2; ++m) {
            aX[m][0] = LDv(Ab + m*16*64 + q0);
            aX[m][1] = LDv(Ab + m*16*64 + q1);
        }
        #pragma unroll
        for (int n = 0; n < 2; ++n) {
            bX[n][0] = LDv(Bb + n*16*64 + q0);
            bX[n][1] = LDv(Bb + n*16*64 + q1);
        }
        __builtin_amdgcn_s_barrier();
        __builtin_amdgcn_s_setprio(1);
        #pragma unroll
        for (int m = 0; m < 2; ++m)
            #pragma unroll
            for (int n = 0; n < 2; ++n) {
                acc[m][n] = __builtin_amdgcn_mfma_f32_16x16x32_bf16(aX[m][0], bX[n][0], acc[m][n],0,0,0);
                acc[m][n] = __builtin_amdgcn_mfma_f32_16x16x32_bf16(aX[m][1], bX[n][1], acc[m][n],0,0,0);
            }
        __builtin_amdgcn_s_setprio(0);
        __builtin_amdgcn_s_barrier();
        // -- P2: read a2-3; MFMA (m2-3)x(n0)
        #pragma unroll
        for (int m = 0; m < 2; ++m) {
            aX[m+2][0] = LDv(Ab + (m+2)*16*64 + q0);
            aX[m+2][1] = LDv(Ab + (m+2)*16*64 + q1);
        }
        __builtin_amdgcn_s_barrier();
        __builtin_amdgcn_s_setprio(1);
        #pragma unroll
        for (int m = 0; m < 2; ++m) {
            acc[m+2][0] = __builtin_amdgcn_mfma_f32_16x16x32_bf16(aX[m+2][0], bX[0][0], acc[m+2][0],0,0,0);
            acc[m+2][0] = __builtin_amdgcn_mfma_f32_16x16x32_bf16(aX[m+2][1], bX[0][1], acc[m+2][0],0,0,0);
        }
        __builtin_amdgcn_s_setprio(0);
        __builtin_amdgcn_s_barrier();
        // -- P3: stage t+2 (buf p free: all reads done in P1/P2); MFMA (m2-3)x(n1)
        if (t + 2 < T) STAGE(t + 2);
        __builtin_amdgcn_s_barrier();
        __builtin_amdgcn_s_setprio(1);
        #pragma unroll
        for (int m = 0; m < 2; ++m) {
            acc[m+2][1] = __builtin_amdgcn_mfma_f32_16x16x32_bf16(aX[m+2][0], bX[1][0], acc[m+2][1],0,0,0);
            acc[m+2][1] = __builtin_amdgcn_mfma_f32_16x16x32_bf16(aX[m+2][1], bX[1][1], acc[m+2][1],0,0,0);
        }
        __builtin_amdgcn_s_setprio(0);
        __builtin_amdgcn_s_barrier();
    }

    // epilogue: C/D layout col=lane&15, row=(lane>>4)*4+reg
    const int fc = lane & 15, r4 = (lane >> 4) * 4;
    float lmax = 0.0f;
    #pragma unroll
    for (int m = 0; m < 4; ++m) {
        const int rb = row0 + wm*64 + m*16 + r4;
        #pragma unroll
        for (int n = 0; n < 2; ++n) {
            const int gc = col0 + wn*32 + n*16 + fc;
            #pragma unroll
            for (int j = 0; j < 4; ++j) {
                const int r = rb + j;
                float v = acc[m][n][j];
                if (EP == 7) {
                    v += bias[gc] + addx[(size_t)r*sAdd + gc];
                    C[(size_t)r*sC + gc] = v;
                    lmax = fmaxf(lmax, fabsf(v));
                } else { // EP == 4
                    C[(size_t)r*sC + gc] = v + addx[(size_t)r*sAdd + gc];
                }
            }
        }
    }
    if (EP == 7) {
        #pragma unroll
        for (int off = 32; off > 0; off >>= 1) lmax = fmaxf(lmax, __shfl_down(lmax, off));
        if (lane == 0) redmax[w] = lmax;
        __syncthreads();
        if (tid == 0) {
            float t = redmax[0];
            #pragma unroll
            for (int i = 1; i < 8; ++i) t = fmaxf(t, redmax[i]);
            atomicMax(gma + ((row0 & (SEQ - 1)) >> 9), __float_as_uint(t));
        }
    }
}

// ----------------------------- MFMA GEMM (m97 128-tile) ---------------------
// EP: 0 C=fp32 | 1 Cb=bf16 clip(v+bias) | 3 Cb=bf16 softplus(v+bias)
template<int EP, bool DUALA, int BN, bool KSPLIT>
__global__ __launch_bounds__(256) void mfma_gemm(
    const unsigned short* __restrict__ A, const unsigned short* __restrict__ A2,
    const unsigned short* __restrict__ B, float* __restrict__ C,
    unsigned short* __restrict__ Cb,
    int M, int N, int K, int sA, int sC,
    const float* __restrict__ bias, int ksl)
{
    constexpr int NF = BN / 32;
    __shared__ __align__(16) unsigned short As[128*32];
    __shared__ __align__(16) unsigned short As2[DUALA ? 128*32 : 8];
    __shared__ __align__(16) unsigned short Bs[BN*32];
    const int tid = threadIdx.x;
    const int lane = tid & 63;
    const int w = tid >> 6;
    const int wm = w >> 1, wn = w & 1;

    int bx = blockIdx.x, by = blockIdx.y;
    if (!KSPLIT) {
        const int gx = gridDim.x;
        const int nwg = gx * gridDim.y;
        int lin = by * gx + bx;
        int nl = (lin & 7) * (nwg >> 3) + (lin >> 3);
        bx = nl % gx; by = nl / gx;
    }
    const int row0 = by * 128, col0 = bx * BN;
    const int srow = lane >> 2;
    const int scol = (lane & 3) * 8;

    int k_begin = 0, k_end = K;
    if (KSPLIT) {
        int z = blockIdx.z;
        k_begin = z * ksl; k_end = k_begin + ksl;
        C += (size_t)z * M * sC;
    }

    f32x4 acc[4][NF];
    #pragma unroll
    for (int m = 0; m < 4; ++m)
        #pragma unroll
        for (int n = 0; n < NF; ++n)
            acc[m][n] = (f32x4){0.f, 0.f, 0.f, 0.f};

    for (int k0 = k_begin; k0 < k_end; k0 += 32) {
        #pragma unroll
        for (int i = 0; i < 2; ++i) {
            const int rbase = w * 32 + i * 16;
            stage16(A + (size_t)(row0 + rbase + srow) * sA + k0 + scol, &As[rbase * 32]);
            if (DUALA)
                stage16(A2 + (size_t)(row0 + rbase + srow) * sA + k0 + scol, &As2[rbase * 32]);
        }
        #pragma unroll
        for (int i = 0; i < BN/64; ++i) {
            const int rbase = (BN == 128) ? (w * 32 + i * 16) : (w * 16);
            if (col0 + rbase < N)
                stage16(B + (size_t)(col0 + rbase + srow) * K + k0 + scol, &Bs[rbase * 32]);
        }
        __syncthreads();

        short8v af[4], bfr[NF], af2[4];
        const int fr = lane & 15, kg = (lane >> 4) * 8;
        #pragma unroll
        for (int m = 0; m < 4; ++m)
            af[m] = *reinterpret_cast<const short8v*>(&As[(wm*64 + m*16 + fr) * 32 + kg]);
        if (DUALA) {
            #pragma unroll
            for (int m = 0; m < 4; ++m)
                af2[m] = *reinterpret_cast<const short8v*>(&As2[(wm*64 + m*16 + fr) * 32 + kg]);
        }
        #pragma unroll
        for (int n = 0; n < NF; ++n)
            bfr[n] = *reinterpret_cast<const short8v*>(&Bs[(wn*(BN/2) + n*16 + fr) * 32 + kg]);

        #pragma unroll
        for (int m = 0; m < 4; ++m)
            #pragma unroll
            for (int n = 0; n < NF; ++n) {
                acc[m][n] = __builtin_amdgcn_mfma_f32_16x16x32_bf16(af[m], bfr[n], acc[m][n], 0, 0, 0);
                if (DUALA)
                    acc[m][n] = __builtin_amdgcn_mfma_f32_16x16x32_bf16(af2[m], bfr[n], acc[m][n], 0, 0, 0);
            }
        __syncthreads();
    }

    const int fc = lane & 15, r4 = (lane >> 4) * 4;
    #pragma unroll
    for (int m = 0; m < 4; ++m) {
        const int grb = row0 + wm*64 + m*16 + r4;
        #pragma unroll
        for (int n = 0; n < NF; ++n) {
            const int gc = col0 + wn*(BN/2) + n*16 + fc;
            if (gc >= N) continue;
            #pragma unroll
            for (int j = 0; j < 4; ++j) {
                const int r = grb + j;
                float v = acc[m][n][j];
                if (EP == 0) {
                    C[(size_t)r*sC + gc] = v;
                } else if (EP == 1) {
                    v += bias[gc];
                    v = fminf(1.0f, fmaxf(-1.0f, v));
                    Cb[(size_t)r*sC + gc] = f2bf(v);
                } else if (EP == 3) {
                    float t = v + bias[gc];
                    t = fmaxf(t, 0.0f) + log1pf(__expf(-fabsf(t)));
                    Cb[(size_t)r*sC + gc] = f2bf(t);
                }
            }
        }
    }
}

// ------------- x_proj split-K combine: xdbl = sum partials; emit bf16 dt ----
__global__ __launch_bounds__(256) void xproj_combine_kernel(
    const float* __restrict__ part,     // [4][NTOK][96]
    float* __restrict__ xdbl,           // [NTOK][96]
    unsigned short* __restrict__ xdt)   // [NTOK][64]
{
    int i = blockIdx.x * 256 + threadIdx.x;
    if (i >= NTOK * 24) return;
    const size_t stride = (size_t)NTOK * 96 / 4;
    float4 v0 = reinterpret_cast<const float4*>(part)[i];
    float4 v1 = reinterpret_cast<const float4*>(part)[i + stride];
    float4 v2 = reinterpret_cast<const float4*>(part)[i + 2*stride];
    float4 v3 = reinterpret_cast<const float4*>(part)[i + 3*stride];
    float4 o;
    o.x = (v0.x + v1.x) + (v2.x + v3.x);
    o.y = (v0.y + v1.y) + (v2.y + v3.y);
    o.z = (v0.z + v1.z) + (v2.z + v3.z);
    o.w = (v0.w + v1.w) + (v2.w + v3.w);
    reinterpret_cast<float4*>(xdbl)[i] = o;
    int row = i / 24, c4 = i % 24;
    if (c4 < 16) {
        ushort4 u;
        u.x = f2bf(o.x); u.y = f2bf(o.y); u.z = f2bf(o.z); u.w = f2bf(o.w);
        reinterpret_cast<ushort4*>(xdt + (size_t)row * 64)[c4] = u;
    }
}

// ------------------- fused quant + LN2 (qx fp32 + u bf16) -------------------
__global__ __launch_bounds__(256) void quant_ln_kernel(
    const float* __restrict__ x2, const unsigned int* __restrict__ gamma_bits,
    const float* __restrict__ g, const float* __restrict__ b,
    float* __restrict__ qx, unsigned short* __restrict__ u)
{
    int row = blockIdx.x, tid = threadIdx.x;
    int grp = (row & (SEQ - 1)) >> 9;
    float gamma = __uint_as_float(gamma_bits[grp]);
    float scale = 128.0f / (gamma + EPS);
    const float lo = -128.0f + EPS, hi = 128.0f - EPS;
    float4 v = reinterpret_cast<const float4*>(x2 + (size_t)row * D_MODEL)[tid];
    float4 qv;
    qv.x = fminf(hi, fmaxf(lo, v.x * scale));
    qv.y = fminf(hi, fmaxf(lo, v.y * scale));
    qv.z = fminf(hi, fmaxf(lo, v.z * scale));
    qv.w = fminf(hi, fmaxf(lo, v.w * scale));
    reinterpret_cast<float4*>(qx + (size_t)row * D_MODEL)[tid] = qv;
    float s = qv.x + qv.y + qv.z + qv.w;
    float q = qv.x*qv.x + qv.y*qv.y + qv.z*qv.z + qv.w*qv.w;
    #pragma unroll
    for (int off = 32; off > 0; off >>= 1) { s += __shfl_down(s, off); q += __shfl_down(q, off); }
    __shared__ float rs[4], rq[4], smean, srstd;
    if ((tid & 63) == 0) { rs[tid >> 6] = s; rq[tid >> 6] = q; }
    __syncthreads();
    if (tid == 0) {
        float ts = rs[0]+rs[1]+rs[2]+rs[3], tq = rq[0]+rq[1]+rq[2]+rq[3];
        float mean = ts * (1.0f / D_MODEL);
        smean = mean;
        srstd = rsqrtf(tq * (1.0f / D_MODEL) - mean*mean + EPS);
    }
    __syncthreads();
    float mean = smean, rstd = srstd;
    float4 gg = reinterpret_cast<const float4*>(g)[tid];
    float4 bb = reinterpret_cast<const float4*>(b)[tid];
    ushort4 o;
    o.x = f2bf((qv.x-mean)*rstd*gg.x + bb.x);
    o.y = f2bf((qv.y-mean)*rstd*gg.y + bb.y);
    o.z = f2bf((qv.z-mean)*rstd*gg.z + bb.z);
    o.w = f2bf((qv.w-mean)*rstd*gg.w + bb.w);
    reinterpret_cast<ushort4*>(u + (size_t)row * D_MODEL)[tid] = o;
}

// -------------- depthwise causal conv + SiLU (bf16 in/out) ------------------
__global__ __launch_bounds__(256) void conv_silu_kernel(const unsigned short* __restrict__ xz,
                                                        const float* __restrict__ conv_w,
                                                        const float* __restrict__ conv_b,
                                                        unsigned short* __restrict__ xcb) {
    int c = blockIdx.x * 256 + threadIdx.x;   // 0..2047
    int m = blockIdx.y;                        // 0..4095
    int b = m >> 11, l = m & (SEQ - 1);
    float4 w4 = reinterpret_cast<const float4*>(conv_w)[c];
    float wv[4] = {w4.x, w4.y, w4.z, w4.w};
    float s = conv_b[c];
    const unsigned short* base = xz + ((size_t)b * SEQ) * 4096 + c;
    #pragma unroll
    for (int k = 0; k < 4; ++k) {
        int ll = l - 3 + k;
        if (ll >= 0) s += bf2f(base[(size_t)ll * 4096]) * wv[k];
    }
    float sig = 1.0f / (1.0f + __expf(-s));
    xcb[(size_t)m * D_INNER + c] = f2bf(s * sig);
}

// ----------------------------- chunked selective scan ------------------------
__device__ __forceinline__ void make_dA(float dA[D_STATE], float dtv,
                                        const float* a, bool pw) {
    if (pw) {
        dA[0] = __expf(dtv * a[0]);
        #pragma unroll
        for (int s = 1; s < D_STATE; ++s) dA[s] = dA[s>>1] * dA[(s-1)>>1];
    } else {
        #pragma unroll
        for (int s = 0; s < D_STATE; ++s) dA[s] = __expf(dtv * a[s]);
    }
}

__global__ __launch_bounds__(256) void scan_partial_kernel(
    const unsigned short* __restrict__ dt, const unsigned short* __restrict__ xcb,
    const float* __restrict__ xdbl, const float* __restrict__ A_log,
    float* __restrict__ Lbuf, float* __restrict__ Sbuf)
{
    int gtid = blockIdx.x * 256 + threadIdx.x;
    int ch = gtid & (NCH - 1);
    int c  = gtid >> 12;
    int b = ch >> 11, d = ch & (D_INNER - 1);
    float a[D_STATE], h[D_STATE];
    bool pw = true;
    #pragma unroll
    for (int s = 0; s < D_STATE; ++s) {
        a[s] = -__expf(A_log[(size_t)d * D_STATE + s]);
        h[s] = 0.0f;
    }
    #pragma unroll
    for (int s = 1; s < D_STATE; ++s)
        pw = pw && (fabsf(a[s] - a[0]*(float)(s+1)) <= 1e-3f * fabsf(a[s]));

    size_t m0 = (size_t)b * SEQ + (size_t)c * CLEN;
    float Ssum = 0.0f;

    float dt_n = bf2f(dt[m0 * D_INNER + d]);
    float x_n  = bf2f(xcb[m0 * D_INNER + d]);
    float4 B_n[4];
    {
        const float* xd = xdbl + m0 * 96;
        #pragma unroll
        for (int i = 0; i < 4; ++i)
            B_n[i] = *reinterpret_cast<const float4*>(xd + DT_RANK + 4*i);
    }

    for (int l = 0; l < CLEN; ++l) {
        float dtv = dt_n, xv = x_n;
        float Bc[D_STATE];
        #pragma unroll
        for (int i = 0; i < 4; ++i) {
            Bc[4*i+0] = B_n[i].x; Bc[4*i+1] = B_n[i].y; Bc[4*i+2] = B_n[i].z; Bc[4*i+3] = B_n[i].w;
        }
        if (l + 1 < CLEN) {
            size_t m1 = m0 + l + 1;
            dt_n = bf2f(dt[m1 * D_INNER + d]);
            x_n  = bf2f(xcb[m1 * D_INNER + d]);
            const float* xd = xdbl + m1 * 96;
            #pragma unroll
            for (int i = 0; i < 4; ++i)
                B_n[i] = *reinterpret_cast<const float4*>(xd + DT_RANK + 4*i);
        }
        Ssum += dtv;
        float dx = dtv * xv;
        float dA[D_STATE];
        make_dA(dA, dtv, a, pw);
        #pragma unroll
        for (int s = 0; s < D_STATE; ++s)
            h[s] = h[s] * dA[s] + dx * Bc[s];
    }
    float4* Lp = reinterpret_cast<float4*>(Lbuf + (size_t)c * (NCH * D_STATE) + (size_t)ch * D_STATE);
    Lp[0] = make_float4(h[0], h[1], h[2], h[3]);
    Lp[1] = make_float4(h[4], h[5], h[6], h[7]);
    Lp[2] = make_float4(h[8], h[9], h[10], h[11]);
    Lp[3] = make_float4(h[12], h[13], h[14], h[15]);
    Sbuf[(size_t)c * NCH + ch] = Ssum;
}

__global__ __launch_bounds__(256) void scan_combine_kernel(
    float* __restrict__ LH, const float* __restrict__ Sbuf,
    const float* __restrict__ A_log)
{
    int gtid = blockIdx.x * 256 + threadIdx.x;
    int s = gtid & (D_STATE - 1);
    int ch = gtid >> 4;
    int d = ch & (D_INNER - 1);
    float a = -__expf(A_log[(size_t)d * D_STATE + s]);
    float h = 0.0f;
    #pragma unroll 4
    for (int c = 0; c < NCHUNK; ++c) {
        size_t idx = (size_t)c * (NCH * D_STATE) + (size_t)ch * D_STATE + s;
        float loc = LH[idx];
        LH[idx] = h;
        float P = __expf(a * Sbuf[(size_t)c * NCH + ch]);
        h = h * P + loc;
    }
}

__global__ __launch_bounds__(256) void scan_final_kernel(
    const unsigned short* __restrict__ dt, const unsigned short* __restrict__ xcb,
    const unsigned short* __restrict__ xzb, const float* __restrict__ xdbl,
    const float* __restrict__ A_log, const float* __restrict__ D_param,
    const float* __restrict__ Hin, unsigned short* __restrict__ yb)
{
    int gtid = blockIdx.x * 256 + threadIdx.x;
    int ch = gtid & (NCH - 1);
    int c  = gtid >> 12;
    int b = ch >> 11, d = ch & (D_INNER - 1);
    float a[D_STATE], h[D_STATE];
    {
        const float4* Hp = reinterpret_cast<const float4*>(
            Hin + (size_t)c * (NCH * D_STATE) + (size_t)ch * D_STATE);
        float4 h0 = Hp[0], h1 = Hp[1], h2 = Hp[2], h3 = Hp[3];
        h[0]=h0.x; h[1]=h0.y; h[2]=h0.z; h[3]=h0.w;
        h[4]=h1.x; h[5]=h1.y; h[6]=h1.z; h[7]=h1.w;
        h[8]=h2.x; h[9]=h2.y; h[10]=h2.z; h[11]=h2.w;
        h[12]=h3.x; h[13]=h3.y; h[14]=h3.z; h[15]=h3.w;
    }
    bool pw = true;
    #pragma unroll
    for (int s = 0; s < D_STATE; ++s)
        a[s] = -__expf(A_log[(size_t)d * D_STATE + s]);
    #pragma unroll
    for (int s = 1; s < D_STATE; ++s)
        pw = pw && (fabsf(a[s] - a[0]*(float)(s+1)) <= 1e-3f * fabsf(a[s]));
    float Dp = D_param[d];

    size_t m0 = (size_t)b * SEQ + (size_t)c * CLEN;
    float dt_n = bf2f(dt[m0 * D_INNER + d]);
    float x_n  = bf2f(xcb[m0 * D_INNER + d]);
    float z_n  = bf2f(xzb[m0 * 4096 + D_INNER + d]);
    float4 B_n[4], C_n[4];
    {
        const float* xd = xdbl + m0 * 96;
        #pragma unroll
        for (int i = 0; i < 4; ++i) {
            B_n[i] = *reinterpret_cast<const float4*>(xd + DT_RANK + 4*i);
            C_n[i] = *reinterpret_cast<const float4*>(xd + DT_RANK + D_STATE + 4*i);
        }
    }

    for (int l = 0; l < CLEN; ++l) {
        float dtv = dt_n, xv = x_n, zv = z_n;
        float Bc[D_STATE], Cc[D_STATE];
        #pragma unroll
        for (int i = 0; i < 4; ++i) {
            Bc[4*i+0] = B_n[i].x; Bc[4*i+1] = B_n[i].y; Bc[4*i+2] = B_n[i].z; Bc[4*i+3] = B_n[i].w;
            Cc[4*i+0] = C_n[i].x; Cc[4*i+1] = C_n[i].y; Cc[4*i+2] = C_n[i].z; Cc[4*i+3] = C_n[i].w;
        }
        if (l + 1 < CLEN) {
            size_t m1 = m0 + l + 1;
            dt_n = bf2f(dt[m1 * D_INNER + d]);
            x_n  = bf2f(xcb[m1 * D_INNER + d]);
            z_n  = bf2f(xzb[m1 * 4096 + D_INNER + d]);
            const float* xd = xdbl + m1 * 96;
            #pragma unroll
            for (int i = 0; i < 4; ++i) {
                B_n[i] = *reinterpret_cast<const float4*>(xd + DT_RANK + 4*i);
                C_n[i] = *reinterpret_cast<const float4*>(xd + DT_RANK + D_STATE + 4*i);
            }
        }
        float dx = dtv * xv;
        float yv = 0.0f;
        float dA[D_STATE];
        make_dA(dA, dtv, a, pw);
        #pragma unroll
        for (int s = 0; s < D_STATE; ++s) {
            h[s] = h[s] * dA[s] + dx * Bc[s];
            yv += h[s] * Cc[s];
        }
        yv += Dp * xv;
        float sig = 1.0f / (1.0f + __expf(-zv));
        yb[(m0 + l) * D_INNER + d] = f2bf(yv * (zv * sig));
    }
}

// ----------------------------- launch ---------------------------------------
extern "C" void kernel_launch(void* const* d_in, const int* in_sizes, int n_in,
                              void* d_out, int out_size, void* d_ws, size_t ws_size,
                              hipStream_t stream) {
    const float* x         = (const float*)d_in[0];
    const float* ln1_g     = (const float*)d_in[1];
    const float* ln1_b     = (const float*)d_in[2];
    const float* ln2_g     = (const float*)d_in[3];
    const float* ln2_b     = (const float*)d_in[4];
    const float* W1        = (const float*)d_in[5];
    const float* b1        = (const float*)d_in[6];
    const float* W2        = (const float*)d_in[7];
    const float* b2        = (const float*)d_in[8];
    const float* in_proj   = (const float*)d_in[9];
    const float* conv_w    = (const float*)d_in[10];
    const float* conv_b    = (const float*)d_in[11];
    const float* x_proj    = (const float*)d_in[12];
    const float* dt_proj   = (const float*)d_in[13];
    const float* dt_proj_b = (const float*)d_in[14];
    const float* A_log     = (const float*)d_in[15];
    const float* D_param   = (const float*)d_in[16];
    const float* out_proj  = (const float*)d_in[17];
    float* out = (float*)d_out;

    // ---- workspace layout (bytes), ~159 MiB (round-10 layout) ----
    char* ws = (char*)d_ws;
    float*          f_x2   = (float*)         (ws + 0);          // 16,777,216  x2/qx
    unsigned short* b_xz   = (unsigned short*)(ws + 16777216);   // 33,554,432  bf16 [xs|z]
    unsigned short* b_dt   = (unsigned short*)(ws + 50331648);   // 16,777,216  dt bf16
    float*          f_xdbl = (float*)         (ws + 83886080);   //  1,572,864
    float*          f_L    = (float*)         (ws + 85458944);   // 16,777,216
    float*          f_xp   = f_L;                                //  alias (consumed before scan)
    float*          f_S    = (float*)         (ws + 102236160);  //  1,048,576
    unsigned int*   f_gamma= (unsigned int*)  (ws + 103284736);  // 64
    unsigned short* b_a1hi = (unsigned short*)(ws + 103284800);  //  8,388,608
    unsigned short* b_a1lo = b_a1hi + 4194304;                   //  8,388,608
    unsigned short* b_y    = b_a1hi;                             //  reuse 16 MB
    unsigned short* b_gated= (unsigned short*)(ws + 120062016);  // 16,777,216
    unsigned short* b_xc   = b_gated;                            //  reuse
    unsigned short* b_u    = (unsigned short*)(ws + 136839232);  //  8,388,608
    unsigned short* b_xdt  = b_u;                                //  reuse 512 KB
    unsigned short* b_w1s  = (unsigned short*)(ws + 145227840);  //  4,194,304
    unsigned short* b_w2s  = (unsigned short*)(ws + 149422144);  //  4,194,304
    unsigned short* b_inpj = (unsigned short*)(ws + 153616448);  //  8,388,608
    unsigned short* b_xpj  = (unsigned short*)(ws + 162005056);  //    393,216
    unsigned short* b_dtpj = (unsigned short*)(ws + 162398272);  //    262,144
    unsigned short* b_outpj= (unsigned short*)(ws + 162660416);  //  4,194,304

    dim3 b256(256);

    // 0. all weight conversions (+ gamma init) in one launch
    f2bf_all_kernel<<<dim3((F4_C6 + 255)/256), b256, 0, stream>>>(
        W1, W2, in_proj, x_proj, dt_proj, out_proj,
        b_w1s, b_w2s, b_inpj, b_xpj, b_dtpj, b_outpj, f_gamma);

    // 1. LN1 -> hi/lo bf16
    ln_hilo_kernel<<<dim3(NTOK), b256, 0, stream>>>(x, ln1_g, ln1_b, b_a1hi, b_a1lo);
    // 2. gated = clip((hi+lo) @ sign(W1)^T + b1) -> bf16   [m97, BN=128, 512 blocks]
    mfma_gemm<1, true, 128, false><<<dim3(16, 32), b256, 0, stream>>>(
        b_a1hi, b_a1lo, b_w1s, nullptr, b_gated, NTOK, D_INNER, D_MODEL, D_MODEL, D_INNER,
        b1, 0);
    // 3. x2 = gated @ sign(W2)^T + b2 + x -> fp32, absmax  [128² 8-phase, 256 blocks]
    mfma_gemm128_8ph<7><<<dim3(8, 32), dim3(512), 0, stream>>>(
        b_gated, b_w2s, f_x2, NTOK, D_MODEL, D_INNER, D_INNER, D_MODEL,
        b2, x, D_MODEL, f_gamma);
    // 4+5. fused quant + LN2 -> qx fp32, u bf16
    quant_ln_kernel<<<dim3(NTOK), b256, 0, stream>>>(f_x2, f_gamma, ln2_g, ln2_b, f_x2, b_u);
    // 6. xz = u @ in_proj^T -> bf16   [256² 8-phase + T2, 256 blocks]
    mfma_gemm256_bf16out<<<dim3(16, 16), dim3(512), 0, stream>>>(
        b_u, b_inpj, b_xz, NTOK, 2*D_INNER, D_MODEL, D_MODEL, 2*D_INNER);
    // 7. conv + silu -> bf16 xc
    conv_silu_kernel<<<dim3(D_INNER/256, NTOK), b256, 0, stream>>>(b_xz, conv_w, conv_b, b_xc);
    // 8. x_dbl partials = xc @ x_proj^T  [split-K x4, 128 blocks]
    mfma_gemm<0, false, 128, true><<<dim3(1, 32, 4), b256, 0, stream>>>(
        b_xc, nullptr, b_xpj, f_xp, nullptr, NTOK, DT_RANK + 2*D_STATE, D_INNER, D_INNER,
        DT_RANK + 2*D_STATE, nullptr, 512);
    // 8b. combine partials -> f_xdbl fp32 + b_xdt bf16
    xproj_combine_kernel<<<dim3((NTOK*24 + 255)/256), b256, 0, stream>>>(f_xp, f_xdbl, b_xdt);
    // 9. dt = softplus(xdt @ dt_proj^T + b) -> bf16  [m97, BN=64, 1024 blocks]
    mfma_gemm<3, false, 64, false><<<dim3(32, 32), b256, 0, stream>>>(
        b_xdt, nullptr, b_dtpj, nullptr, b_dt, NTOK, D_INNER, DT_RANK, DT_RANK, D_INNER,
        dt_proj_b, 0);
    // 10. chunked scan
    scan_partial_kernel<<<dim3(NCH*NCHUNK/256), b256, 0, stream>>>(
        b_dt, b_xc, f_xdbl, A_log, f_L, f_S);
    scan_combine_kernel<<<dim3(NCH*D_STATE/256), b256, 0, stream>>>(f_L, f_S, A_log);
    scan_final_kernel<<<dim3(NCH*NCHUNK/256), b256, 0, stream>>>(
        b_dt, b_xc, b_xz, f_xdbl, A_log, D_param, f_L, b_y);
    // 11. out = y @ out_proj^T + qx -> fp32  [128² 8-phase, 256 blocks]
    mfma_gemm128_8ph<4><<<dim3(8, 32), dim3(512), 0, stream>>>(
        b_y, b_outpj, out, NTOK, D_MODEL, D_INNER, D_INNER, D_MODEL,
        nullptr, f_x2, D_MODEL, nullptr);
}